// Round 14
// baseline (2769.993 us; speedup 1.0000x reference)
//
#include <hip/hip_runtime.h>

#define TOK 32768          // B*N
#define DMODEL 1024
#define NSEQ 8192
#define NCHK 32            // chunks per sequence
#define CHUNKC 256
#define KDIM 1024
#define NCOL 131072        // B*NCHK*DMODEL scan columns
#define LOG2E 1.44269504f

typedef __attribute__((ext_vector_type(8))) short bf16x8;
typedef __attribute__((ext_vector_type(4))) float f32x4;

__device__ __forceinline__ unsigned short f2bf(float f) {
  unsigned u = __float_as_uint(f);
  u += 0x7fffu + ((u >> 16) & 1u);
  return (unsigned short)(u >> 16);
}
__device__ __forceinline__ float bf2f(unsigned short h) {
  return __uint_as_float(((unsigned)h) << 16);
}
__device__ __forceinline__ float sigm(float x) {   // sigmoid via exp2+rcp
  return __builtin_amdgcn_rcpf(1.f + exp2f(-LOG2E * x));
}
__device__ __forceinline__ float softplus_cl(float a) {
  const float e2 = exp2f(-LOG2E * fabsf(a));
  const float sp = fmaxf(a, 0.f) + 0.69314718f * log2f(1.f + e2);
  return fminf(fmaxf(sp, 0.001f), 2.0f);
}

typedef __attribute__((address_space(3))) unsigned int lds_u32_t;
typedef const __attribute__((address_space(1))) unsigned int glb_u32_t;

__device__ __forceinline__ void gl_lds16(const void* g, void* l) {
  __builtin_amdgcn_global_load_lds((glb_u32_t*)g, (lds_u32_t*)l, 16, 0, 0);
}

// ------ merged pre-pass: {W1T,W2T transpose->bf16, RoPE table} + rmsconv ----------
__global__ __launch_bounds__(256) void pre_k(const float* __restrict__ x,
                                             const float* __restrict__ scale,
                                             const float* __restrict__ cw,
                                             const float* __restrict__ cbias,
                                             unsigned short* __restrict__ xc,
                                             const float* __restrict__ w1,
                                             const float* __restrict__ w2,
                                             unsigned short* __restrict__ w1t,
                                             unsigned short* __restrict__ w2t,
                                             float2* __restrict__ tab) {
  __shared__ float tile[32][33];
  __shared__ float red[11][4];
  const int bid = blockIdx.x;
  const int t = threadIdx.x;
  if (bid < 4096) {        // transpose W[R=1024][C] -> WT[C][1024]
    const float* in;
    unsigned short* out;
    int c0, r0;
    if (bid < 3072) { in = w1; out = w1t; c0 = (bid % 96) * 32; r0 = (bid / 96) * 32; }
    else            { in = w2; out = w2t; c0 = ((bid - 3072) & 31) * 32; r0 = ((bid - 3072) >> 5) * 32; }
    const int C = (bid < 3072) ? 3072 : 1024;
    const int tx = t & 31, ty = t >> 5;
#pragma unroll
    for (int i = 0; i < 32; i += 8)
      tile[ty + i][tx] = in[(long)(r0 + ty + i) * C + c0 + tx];
    __syncthreads();
#pragma unroll
    for (int i = 0; i < 32; i += 8)
      out[(long)(c0 + ty + i) * 1024 + r0 + tx] = f2bf(tile[tx][ty + i]);
  } else if (bid < 5120) { // RoPE table: 8192*32 entries
    const int i = (bid - 4096) * 256 + t;
    const int f = i & 31, n = i >> 5;
    const float invf = exp2f(-(float)f * (13.287712379549449f / 32.0f));
    const float ang = (float)n * invf;
    tab[i] = make_float2(cosf(ang), sinf(ang));
  } else {                 // fused RMSNorm + depthwise conv(K=4) + SiLU
    const long row0 = (long)(bid - 5120) * 8;
    const bool seqstart = ((row0 & (NSEQ - 1)) == 0);
    const float4 sc = ((const float4*)scale)[t];
    float4 vr[11];
#pragma unroll
    for (int i = 0; i < 11; ++i) {
      if (i < 3 && seqstart) {
        vr[i] = make_float4(0.f, 0.f, 0.f, 0.f);
      } else {
        vr[i] = ((const float4*)(x + (row0 - 3 + i) * DMODEL))[t];
      }
      float ss = vr[i].x * vr[i].x + vr[i].y * vr[i].y + vr[i].z * vr[i].z + vr[i].w * vr[i].w;
#pragma unroll
      for (int off = 32; off > 0; off >>= 1) ss += __shfl_down(ss, off);
      if ((t & 63) == 0) red[i][t >> 6] = ss;
    }
    __syncthreads();
#pragma unroll
    for (int i = 0; i < 11; ++i) {
      const float tot = red[i][0] + red[i][1] + red[i][2] + red[i][3];
      const float rr = rsqrtf(tot * (1.0f / DMODEL) + 1e-6f);
      vr[i].x = fminf(fmaxf(vr[i].x * rr * sc.x, -60000.f), 60000.f);
      vr[i].y = fminf(fmaxf(vr[i].y * rr * sc.y, -60000.f), 60000.f);
      vr[i].z = fminf(fmaxf(vr[i].z * rr * sc.z, -60000.f), 60000.f);
      vr[i].w = fminf(fmaxf(vr[i].w * rr * sc.w, -60000.f), 60000.f);
    }
    const int d0 = t * 4;
    float wl[4][4];
#pragma unroll
    for (int j = 0; j < 4; ++j) {
      const float4 t4 = *(const float4*)(cw + (d0 + j) * 4);
      wl[j][0] = t4.x; wl[j][1] = t4.y; wl[j][2] = t4.z; wl[j][3] = t4.w;
    }
    const float4 cb4 = ((const float4*)cbias)[t];
#pragma unroll
    for (int orow = 0; orow < 8; ++orow) {
      float o[4] = {0.f, 0.f, 0.f, 0.f};
#pragma unroll
      for (int k = 0; k < 4; ++k) {
        const float4 xv = vr[orow + k];
        o[0] += xv.x * wl[0][k]; o[1] += xv.y * wl[1][k];
        o[2] += xv.z * wl[2][k]; o[3] += xv.w * wl[3][k];
      }
      ushort4 st;
      { const float a = o[0] + cb4.x; st.x = f2bf(a * sigm(a)); }
      { const float a = o[1] + cb4.y; st.y = f2bf(a * sigm(a)); }
      { const float a = o[2] + cb4.z; st.z = f2bf(a * sigm(a)); }
      { const float a = o[3] + cb4.w; st.w = f2bf(a * sigm(a)); }
      *(ushort4*)(xc + (row0 + orow) * DMODEL + d0) = st;
    }
  }
}

// ---------------- GEMM: 256x256 tile, asymmetric slot ring (A x2, B x3) -----------
// 8 waves (2M x 4N), per-wave 128x64 (acc[8][4]), BK=32, LDS 80KB -> 2 blocks/CU.
// Ring: iter t issues A(t+1)->slot (t+1)&1 and B(t+2)->slot (t+2)%3, computes
// (t&1, t%3), then counted vmcnt(2) (drains exactly B(t+1),A(t+1), leaves B(t+2)).
// One raw barrier/iter + sched_barrier pin; T5 setprio; T2 granule swizzle.
// EPI==0: plain bf16 store (3072 cols). EPI==1: resid+f32 (1024 cols).
template <int EPI, int NBN, int SBN>
__global__ __launch_bounds__(512, 4) void gemm_bt(const unsigned short* __restrict__ A,
                                                  const unsigned short* __restrict__ BT,
                                                  unsigned short* __restrict__ ob,
                                                  float* __restrict__ of,
                                                  const float* __restrict__ resid) {
  __shared__ unsigned short As[2][8192];   // [slot][256*32]
  __shared__ unsigned short Bs[3][8192];
  const int tid = threadIdx.x;
  const int l = tid & 63;
  const int w = tid >> 6;            // wave 0..7
  const int wr = w >> 2, wc = w & 3; // 2M x 4N
  constexpr int NC = (EPI == 0) ? 3072 : 1024;
  constexpr int NKT = KDIM / 32;

  // T1: XCD round-robin + per-XCD 4bm x SBN supertiles; 16 bm/XCD (gridDim.y=128)
  constexpr int BPS = 4 * SBN;
  constexpr int NBNS = NBN / SBN;
  const int lin = blockIdx.y * NBN + blockIdx.x;
  const int xcd = lin & 7;
  const int g = lin >> 3;
  const int s = g / BPS;
  const int r = g - s * BPS;
  const int bmo = r / SBN;
  const int bno = r - bmo * SBN;
  const int bmS = s / NBNS;
  const int bnS = s - bmS * NBNS;
  const int bm = xcd * 16 + bmS * 4 + bmo;
  const int bn = bnS * SBN + bno;

  f32x4 acc[8][4];
#pragma unroll
  for (int m = 0; m < 8; ++m)
#pragma unroll
    for (int n = 0; n < 4; ++n) acc[m][n] = {0.f, 0.f, 0.f, 0.f};

  // staging: one gl_lds16 wave-call = 16 rows x 64B. lane l -> row l>>2, granule l&3
  // T2 pre-swizzled source granule, key=(row>>1)&3 = (l>>3)&3
  const int srcc = (((l & 3) ^ ((l >> 3) & 3)) * 8);
  const unsigned short* aG0 = A + ((long)(bm * 256 + w * 32 + (l >> 2))) * KDIM + srcc;
  const unsigned short* bG0 = BT + ((long)(bn * 256 + w * 32 + (l >> 2))) * KDIM + srcc;
  const int wL0 = w * 1024;          // wave-uniform LDS dest (elements)

#define STAGE_A(slot, k0)                                        \
  { gl_lds16(aG0 + (k0),            &As[slot][wL0]);             \
    gl_lds16(aG0 + (k0) + 16*KDIM,  &As[slot][wL0 + 512]); }
#define STAGE_B(slot, k0)                                        \
  { gl_lds16(bG0 + (k0),            &Bs[slot][wL0]);             \
    gl_lds16(bG0 + (k0) + 16*KDIM,  &Bs[slot][wL0 + 512]); }

  // read-side swizzled k-granule, key=(row>>1)&3 = (l>>1)&3
  const int eoff = (((l >> 4) ^ ((l >> 1) & 3)) * 8);
  const int aRowOff = (wr * 128 + (l & 15)) * 32 + eoff;   // + m*512
  const int bRowOff = (wc * 64 + (l & 15)) * 32 + eoff;    // + n*512

  auto compute = [&](int as_, int bs_) {
    const unsigned short* Ab = &As[as_][0];
    const unsigned short* Bb = &Bs[bs_][0];
    bf16x8 af[8], bfr[4];
#pragma unroll
    for (int m = 0; m < 8; ++m) af[m] = *(const bf16x8*)&Ab[aRowOff + m * 512];
#pragma unroll
    for (int n = 0; n < 4; ++n) bfr[n] = *(const bf16x8*)&Bb[bRowOff + n * 512];
    __builtin_amdgcn_s_setprio(1);
#pragma unroll
    for (int m = 0; m < 8; ++m)
#pragma unroll
      for (int n = 0; n < 4; ++n)
        acc[m][n] = __builtin_amdgcn_mfma_f32_16x16x32_bf16(af[m], bfr[n], acc[m][n], 0, 0, 0);
    __builtin_amdgcn_s_setprio(0);
  };

  // prologue: A0,B0,A1,B1,B2 issued; wait A0,B0 landed (leave A1,B1,B2 = 6 calls)
  STAGE_A(0, 0);
  STAGE_B(0, 0);
  STAGE_A(1, 32);
  STAGE_B(1, 32);
  STAGE_B(2, 64);
  asm volatile("s_waitcnt vmcnt(6)" ::: "memory");
  __builtin_amdgcn_s_barrier();
  __builtin_amdgcn_sched_barrier(0);

  for (int t = 0; t < NKT - 2; ++t) {
    STAGE_A((t + 1) & 1, (t + 1) * 32);      // WAR: slot held A(t-1), reads done
    STAGE_B((t + 2) % 3, (t + 2) * 32);      // WAR: slot held B(t-1), reads done
    compute(t & 1, t % 3);
    asm volatile("s_waitcnt vmcnt(2)" ::: "memory");  // A(t+1),B(t+1) landed
    __builtin_amdgcn_s_barrier();
    __builtin_amdgcn_sched_barrier(0);
  }
  // iter NKT-2: stage last A only
  STAGE_A((NKT - 1) & 1, (NKT - 1) * 32);
  compute((NKT - 2) & 1, (NKT - 2) % 3);
  asm volatile("s_waitcnt vmcnt(0)" ::: "memory");    // A(NKT-1),B(NKT-1) landed
  __builtin_amdgcn_s_barrier();
  __builtin_amdgcn_sched_barrier(0);
  compute((NKT - 1) & 1, (NKT - 1) % 3);
#undef STAGE_A
#undef STAGE_B

  const int rbase = bm * 256 + wr * 128;
  const int cbase = bn * 256 + wc * 64;
  const int lr4 = (l >> 4) * 4;
  const int lc16 = l & 15;

  if constexpr (EPI == 0) {
#pragma unroll
    for (int m = 0; m < 8; ++m)
#pragma unroll
      for (int n = 0; n < 4; ++n) {
        const int col = cbase + n * 16 + lc16;
#pragma unroll
        for (int j2 = 0; j2 < 4; ++j2) {
          const int row = rbase + m * 16 + lr4 + j2;
          ob[(long)row * NC + col] = f2bf(acc[m][n][j2]);
        }
      }
  } else {
#pragma unroll
    for (int m = 0; m < 8; ++m)
#pragma unroll
      for (int n = 0; n < 4; ++n) {
        const int col = cbase + n * 16 + lc16;
#pragma unroll
        for (int j2 = 0; j2 < 4; ++j2) {
          const int row = rbase + m * 16 + lr4 + j2;
          const long o = (long)row * NC + col;
          of[o] = resid[o] + acc[m][n][j2];
        }
      }
  }
}

// ------- scan pass 1 (4-way parallel, RECOMPUTE): Llast, bout + seg spills --------
__global__ __launch_bounds__(256) void scan1_k(const unsigned short* __restrict__ fu,
                                               const float* __restrict__ dt_bias,
                                               const float2* __restrict__ tab,
                                               float* __restrict__ Llast,
                                               float* __restrict__ bout,
                                               float* __restrict__ segb,
                                               float* __restrict__ scab) {
  __shared__ float Ssum[4][64];
  __shared__ float Ssca[4][64];
  const int t = threadIdx.x;
  const int lane = t & 63, seg = t >> 6;
  const int cid = blockIdx.x * 64 + lane;     // 0..131071
  const int d = cid & 1023;
  const int ch = (cid >> 10) & 31;
  const int b = cid >> 15;
  const long base = ((long)b * NSEQ + ch * CHUNKC + seg * 64) * 3072 + d;
  const float bias = dt_bias[d];
  const int f = d & 31;
  const bool hi = (d & 32) != 0;
  const int po = hi ? -32 : 32;
  float segsum = 0.f;
#pragma unroll 8
  for (int i = 0; i < 64; ++i)
    segsum += softplus_cl(bf2f(fu[base + (long)i * 3072]) + bias);
  Ssum[seg][lane] = segsum;
  segb[seg * NCOL + cid] = segsum;
  __syncthreads();
  float basev = 0.f;
  for (int k = 0; k < seg; ++k) basev -= Ssum[k][lane];   // wave-uniform trip count
  const int posbase = ch * CHUNKC + seg * 64;
  float run = basev, s = 0.f;
#pragma unroll 4
  for (int i = 0; i < 64; ++i) {
    const long o = base + (long)i * 3072;
    const float dtv = softplus_cl(bf2f(fu[o]) + bias);
    const float own = bf2f(fu[o + 1024]);
    const float oth = bf2f(fu[o + 1024 + po]);
    const float2 cs = tab[(posbase + i) * 32 + f];
    const float vr = own * cs.x + (hi ? oth * cs.y : -oth * cs.y);
    run -= dtv;
    const float L = fminf(fmaxf(run, -20.f), 0.f);
    s += exp2f(-LOG2E * L) * (vr * dtv);
  }
  Ssca[seg][lane] = s;
  scab[seg * NCOL + cid] = s;
  __syncthreads();
  if (seg == 0) {
    const float tot = Ssum[0][lane] + Ssum[1][lane] + Ssum[2][lane] + Ssum[3][lane];
    const float Ll = fminf(fmaxf(-tot, -20.f), 0.f);
    const float st = Ssca[0][lane] + Ssca[1][lane] + Ssca[2][lane] + Ssca[3][lane];
    Llast[cid] = Ll;
    bout[cid] = exp2f(LOG2E * Ll) * st;
  }
}

// ------- scan pass 3 (single pass, INLINE carry): final bf16 IN PLACE over v ------
__global__ __launch_bounds__(256) void scan3_k(unsigned short* fu,
                                               const float* __restrict__ dt_bias,
                                               const float2* __restrict__ tab,
                                               const float* __restrict__ Llast,
                                               const float* __restrict__ bout,
                                               const float* __restrict__ segb,
                                               const float* __restrict__ scab) {
  const int t = threadIdx.x;
  const int lane = t & 63, seg = t >> 6;
  const int cid = blockIdx.x * 64 + lane;
  const int d = cid & 1023;
  const int ch = (cid >> 10) & 31;
  const int b = cid >> 15;
  const long base = ((long)b * NSEQ + ch * CHUNKC + seg * 64) * 3072 + d;
  const float bias = dt_bias[d];
  const int f = d & 31;
  const bool hi = (d & 32) != 0;
  const int po = hi ? -32 : 32;
  // ---- inline scan2: carry for (b, ch, d), identical order to the old kernel ----
  const long cb2 = (long)b * (NCHK * DMODEL) + d;
  float run2 = 0.f, stab = -1e30f;
#pragma unroll
  for (int c2 = 0; c2 < NCHK; ++c2) {
    run2 += Llast[cb2 + c2 * DMODEL];
    stab = fmaxf(stab, fminf(fmaxf(run2, -80.f), 0.f));
  }
  float ce = 0.f;
  {
    float run3 = 0.f, acc = 0.f;
    for (int c2 = 0; c2 <= ch; ++c2) {        // block-uniform bound
      run3 += Llast[cb2 + c2 * DMODEL];
      const float cdv = fminf(fmaxf(run3, -80.f), 0.f);
      const float ncd = fminf(fmaxf(cdv - stab, -20.f), 0.f);
      if (c2 == ch) ce = acc * exp2f(LOG2E * ncd);
      else acc += bout[cb2 + c2 * DMODEL] * exp2f(-LOG2E * ncd);
    }
  }
  // ---- segment bases from scan1 spills ----
  float basev = 0.f, sbase = 0.f;
  for (int k = 0; k < seg; ++k) {             // wave-uniform trip count
    basev -= segb[k * NCOL + cid];
    sbase += scab[k * NCOL + cid];
  }
  const int posbase = ch * CHUNKC + seg * 64;
  float run = basev, s = sbase;
#pragma unroll 4
  for (int i = 0; i < 64; ++i) {
    const long o = base + (long)i * 3072;
    const float dtv = softplus_cl(bf2f(fu[o]) + bias);
    const float own = bf2f(fu[o + 1024]);
    const float oth = bf2f(fu[o + 1024 + po]);
    const float2 cs = tab[(posbase + i) * 32 + f];
    const float vr = own * cs.x + (hi ? oth * cs.y : -oth * cs.y);
    run -= dtv;
    const float L = fminf(fmaxf(run, -20.f), 0.f);
    s += exp2f(-LOG2E * L) * (vr * dtv);
    fu[o + 1024] = f2bf(exp2f(LOG2E * L) * (s + ce));
  }
}

// -------- head mix (16x16) * sigmoid(gate_raw) -> A2 bf16 (ushort2 packed) --------
__global__ __launch_bounds__(256) void headmix_k(const unsigned short* __restrict__ fu,
                                                 const float* __restrict__ hm,
                                                 unsigned short* __restrict__ A2) {
  __shared__ float mixs[256];
  const int t = threadIdx.x;
  mixs[t] = hm[t];
  __syncthreads();
  const long row = (long)blockIdx.x * 8 + (t >> 5);   // 8 rows/block
  const int dd = (t & 31) * 2;
  const unsigned short* fv0 = fu + row * 3072 + 1024 + dd;   // final (over v)
  const unsigned short* gv0 = fu + row * 3072 + 2048 + dd;   // gate raw
  unsigned fvp[16];
#pragma unroll
  for (int h = 0; h < 16; ++h) fvp[h] = *(const unsigned*)(fv0 + h * 64);
#pragma unroll
  for (int m = 0; m < 16; ++m) {
    float o0 = 0.f, o1 = 0.f;
#pragma unroll
    for (int h = 0; h < 16; ++h) {
      const float mh = mixs[h * 16 + m];
      o0 += bf2f((unsigned short)(fvp[h] & 0xffffu)) * mh;
      o1 += bf2f((unsigned short)(fvp[h] >> 16)) * mh;
    }
    const unsigned gp = *(const unsigned*)(gv0 + m * 64);
    const unsigned r0 = (unsigned)f2bf(o0 * sigm(bf2f((unsigned short)(gp & 0xffffu))));
    const unsigned r1 = (unsigned)f2bf(o1 * sigm(bf2f((unsigned short)(gp >> 16))));
    *(unsigned*)(A2 + row * DMODEL + m * 64 + dd) = r0 | (r1 << 16);
  }
}

extern "C" void kernel_launch(void* const* d_in, const int* in_sizes, int n_in,
                              void* d_out, int out_size, void* d_ws, size_t ws_size,
                              hipStream_t stream) {
  const float* x        = (const float*)d_in[0];
  const float* nscale   = (const float*)d_in[1];
  const float* conv_w   = (const float*)d_in[2];
  const float* conv_b   = (const float*)d_in[3];
  const float* in_proj  = (const float*)d_in[4];
  const float* dt_bias  = (const float*)d_in[5];
  const float* head_mix = (const float*)d_in[6];
  const float* out_proj = (const float*)d_in[7];
  float* out = (float*)d_out;

  char* p = (char*)d_ws;
  unsigned short* W1T = (unsigned short*)p; p += (size_t)3072 * 1024 * 2;
  unsigned short* W2T = (unsigned short*)p; p += (size_t)1024 * 1024 * 2;
  float2* tab  = (float2*)p; p += (size_t)NSEQ * 32 * sizeof(float2);
  float* Llast = (float*)p;  p += (size_t)NCOL * 4;
  float* bout  = (float*)p;  p += (size_t)NCOL * 4;
  float* segb  = (float*)p;  p += (size_t)4 * NCOL * 4;
  float* scab  = (float*)p;  p += (size_t)4 * NCOL * 4;
  unsigned short* fusedb = (unsigned short*)p; p += (size_t)TOK * 3072 * 2;
  unsigned short* xc     = (unsigned short*)p; p += (size_t)TOK * DMODEL * 2; // reused: A2

  pre_k<<<5120 + TOK / 8, 256, 0, stream>>>(x, nscale, conv_w, conv_b, xc,
                                            in_proj, out_proj, W1T, W2T, tab);

  gemm_bt<0, 12, 6><<<dim3(12, 128), 512, 0, stream>>>(xc, W1T, fusedb, nullptr, nullptr);
  scan1_k<<<2048, 256, 0, stream>>>(fusedb, dt_bias, tab, Llast, bout, segb, scab);
  scan3_k<<<2048, 256, 0, stream>>>(fusedb, dt_bias, tab, Llast, bout, segb, scab);
  headmix_k<<<TOK / 8, 256, 0, stream>>>(fusedb, head_mix, xc /* A2 */);
  gemm_bt<1, 4, 4><<<dim3(4, 128), 512, 0, stream>>>(xc, W2T, nullptr, out, x);
}

// Round 15
// 621.538 us; speedup vs baseline: 4.4567x; 4.4567x over previous
//
#include <hip/hip_runtime.h>

#define TOK 32768          // B*N
#define DMODEL 1024
#define NSEQ 8192
#define NCHK 32            // chunks per sequence
#define CHUNKC 256
#define KDIM 1024
#define NCOL 131072        // B*NCHK*DMODEL scan columns
#define LOG2E 1.44269504f

typedef __attribute__((ext_vector_type(8))) short bf16x8;
typedef __attribute__((ext_vector_type(4))) float f32x4;

__device__ __forceinline__ unsigned short f2bf(float f) {
  unsigned u = __float_as_uint(f);
  u += 0x7fffu + ((u >> 16) & 1u);
  return (unsigned short)(u >> 16);
}
__device__ __forceinline__ float bf2f(unsigned short h) {
  return __uint_as_float(((unsigned)h) << 16);
}
__device__ __forceinline__ float sigm(float x) {   // sigmoid via exp2+rcp
  return __builtin_amdgcn_rcpf(1.f + exp2f(-LOG2E * x));
}
__device__ __forceinline__ float softplus_cl(float a) {
  const float e2 = exp2f(-LOG2E * fabsf(a));
  const float sp = fmaxf(a, 0.f) + 0.69314718f * log2f(1.f + e2);
  return fminf(fmaxf(sp, 0.001f), 2.0f);
}

typedef __attribute__((address_space(3))) unsigned int lds_u32_t;
typedef const __attribute__((address_space(1))) unsigned int glb_u32_t;

__device__ __forceinline__ void gl_lds16(const void* g, void* l) {
  __builtin_amdgcn_global_load_lds((glb_u32_t*)g, (lds_u32_t*)l, 16, 0, 0);
}

// ------ merged pre-pass: {W1T,W2T transpose->bf16, RoPE table} + rmsconv ----------
__global__ __launch_bounds__(256) void pre_k(const float* __restrict__ x,
                                             const float* __restrict__ scale,
                                             const float* __restrict__ cw,
                                             const float* __restrict__ cbias,
                                             unsigned short* __restrict__ xc,
                                             const float* __restrict__ w1,
                                             const float* __restrict__ w2,
                                             unsigned short* __restrict__ w1t,
                                             unsigned short* __restrict__ w2t,
                                             float2* __restrict__ tab) {
  __shared__ float tile[32][33];
  __shared__ float red[11][4];
  const int bid = blockIdx.x;
  const int t = threadIdx.x;
  if (bid < 4096) {        // transpose W[R=1024][C] -> WT[C][1024]
    const float* in;
    unsigned short* out;
    int c0, r0;
    if (bid < 3072) { in = w1; out = w1t; c0 = (bid % 96) * 32; r0 = (bid / 96) * 32; }
    else            { in = w2; out = w2t; c0 = ((bid - 3072) & 31) * 32; r0 = ((bid - 3072) >> 5) * 32; }
    const int C = (bid < 3072) ? 3072 : 1024;
    const int tx = t & 31, ty = t >> 5;
#pragma unroll
    for (int i = 0; i < 32; i += 8)
      tile[ty + i][tx] = in[(long)(r0 + ty + i) * C + c0 + tx];
    __syncthreads();
#pragma unroll
    for (int i = 0; i < 32; i += 8)
      out[(long)(c0 + ty + i) * 1024 + r0 + tx] = f2bf(tile[tx][ty + i]);
  } else if (bid < 5120) { // RoPE table: 8192*32 entries
    const int i = (bid - 4096) * 256 + t;
    const int f = i & 31, n = i >> 5;
    const float invf = exp2f(-(float)f * (13.287712379549449f / 32.0f));
    const float ang = (float)n * invf;
    tab[i] = make_float2(cosf(ang), sinf(ang));
  } else {                 // fused RMSNorm + depthwise conv(K=4) + SiLU
    const long row0 = (long)(bid - 5120) * 8;
    const bool seqstart = ((row0 & (NSEQ - 1)) == 0);
    const float4 sc = ((const float4*)scale)[t];
    float4 vr[11];
#pragma unroll
    for (int i = 0; i < 11; ++i) {
      if (i < 3 && seqstart) {
        vr[i] = make_float4(0.f, 0.f, 0.f, 0.f);
      } else {
        vr[i] = ((const float4*)(x + (row0 - 3 + i) * DMODEL))[t];
      }
      float ss = vr[i].x * vr[i].x + vr[i].y * vr[i].y + vr[i].z * vr[i].z + vr[i].w * vr[i].w;
#pragma unroll
      for (int off = 32; off > 0; off >>= 1) ss += __shfl_down(ss, off);
      if ((t & 63) == 0) red[i][t >> 6] = ss;
    }
    __syncthreads();
#pragma unroll
    for (int i = 0; i < 11; ++i) {
      const float tot = red[i][0] + red[i][1] + red[i][2] + red[i][3];
      const float rr = rsqrtf(tot * (1.0f / DMODEL) + 1e-6f);
      vr[i].x = fminf(fmaxf(vr[i].x * rr * sc.x, -60000.f), 60000.f);
      vr[i].y = fminf(fmaxf(vr[i].y * rr * sc.y, -60000.f), 60000.f);
      vr[i].z = fminf(fmaxf(vr[i].z * rr * sc.z, -60000.f), 60000.f);
      vr[i].w = fminf(fmaxf(vr[i].w * rr * sc.w, -60000.f), 60000.f);
    }
    const int d0 = t * 4;
    float wl[4][4];
#pragma unroll
    for (int j = 0; j < 4; ++j) {
      const float4 t4 = *(const float4*)(cw + (d0 + j) * 4);
      wl[j][0] = t4.x; wl[j][1] = t4.y; wl[j][2] = t4.z; wl[j][3] = t4.w;
    }
    const float4 cb4 = ((const float4*)cbias)[t];
#pragma unroll
    for (int orow = 0; orow < 8; ++orow) {
      float o[4] = {0.f, 0.f, 0.f, 0.f};
#pragma unroll
      for (int k = 0; k < 4; ++k) {
        const float4 xv = vr[orow + k];
        o[0] += xv.x * wl[0][k]; o[1] += xv.y * wl[1][k];
        o[2] += xv.z * wl[2][k]; o[3] += xv.w * wl[3][k];
      }
      ushort4 st;
      { const float a = o[0] + cb4.x; st.x = f2bf(a * sigm(a)); }
      { const float a = o[1] + cb4.y; st.y = f2bf(a * sigm(a)); }
      { const float a = o[2] + cb4.z; st.z = f2bf(a * sigm(a)); }
      { const float a = o[3] + cb4.w; st.w = f2bf(a * sigm(a)); }
      *(ushort4*)(xc + (row0 + orow) * DMODEL + d0) = st;
    }
  }
}

// ---------------- GEMM: 256x256 tile, asymmetric slot ring (A x2, B x3) -----------
// 8 waves (2M x 4N), per-wave 128x64 (acc[8][4]), BK=32, LDS 80KB -> 2 blocks/CU
// (LDS-limited; NO min-waves launch bound — R14's ",4" capped VGPR at 64 and
// spilled the accumulator; R9 measured 112 VGPR spill-free at this shape).
// Ring: iter t issues A(t+1)->slot (t+1)&1 and B(t+2)->slot (t+2)%3, computes
// (t&1, t%3), then counted vmcnt(2) (drains exactly A(t+1),B(t+1), leaves B(t+2)).
// One raw barrier/iter + sched_barrier pin; T5 setprio; T2 granule swizzle.
// EPI==0: plain bf16 store (3072 cols). EPI==1: resid+f32 (1024 cols).
template <int EPI, int NBN, int SBN>
__global__ __launch_bounds__(512) void gemm_bt(const unsigned short* __restrict__ A,
                                               const unsigned short* __restrict__ BT,
                                               unsigned short* __restrict__ ob,
                                               float* __restrict__ of,
                                               const float* __restrict__ resid) {
  __shared__ unsigned short As[2][8192];   // [slot][256*32]
  __shared__ unsigned short Bs[3][8192];
  const int tid = threadIdx.x;
  const int l = tid & 63;
  const int w = tid >> 6;            // wave 0..7
  const int wr = w >> 2, wc = w & 3; // 2M x 4N
  constexpr int NC = (EPI == 0) ? 3072 : 1024;
  constexpr int NKT = KDIM / 32;

  // T1: XCD round-robin + per-XCD 4bm x SBN supertiles; 16 bm/XCD (gridDim.y=128)
  constexpr int BPS = 4 * SBN;
  constexpr int NBNS = NBN / SBN;
  const int lin = blockIdx.y * NBN + blockIdx.x;
  const int xcd = lin & 7;
  const int g = lin >> 3;
  const int s = g / BPS;
  const int r = g - s * BPS;
  const int bmo = r / SBN;
  const int bno = r - bmo * SBN;
  const int bmS = s / NBNS;
  const int bnS = s - bmS * NBNS;
  const int bm = xcd * 16 + bmS * 4 + bmo;
  const int bn = bnS * SBN + bno;

  f32x4 acc[8][4];
#pragma unroll
  for (int m = 0; m < 8; ++m)
#pragma unroll
    for (int n = 0; n < 4; ++n) acc[m][n] = {0.f, 0.f, 0.f, 0.f};

  // staging: one gl_lds16 wave-call = 16 rows x 64B. lane l -> row l>>2, granule l&3
  // T2 pre-swizzled source granule, key=(row>>1)&3 = (l>>3)&3
  const int srcc = (((l & 3) ^ ((l >> 3) & 3)) * 8);
  const unsigned short* aG0 = A + ((long)(bm * 256 + w * 32 + (l >> 2))) * KDIM + srcc;
  const unsigned short* bG0 = BT + ((long)(bn * 256 + w * 32 + (l >> 2))) * KDIM + srcc;
  const int wL0 = w * 1024;          // wave-uniform LDS dest (elements)

#define STAGE_A(slot, k0)                                        \
  { gl_lds16(aG0 + (k0),            &As[slot][wL0]);             \
    gl_lds16(aG0 + (k0) + 16*KDIM,  &As[slot][wL0 + 512]); }
#define STAGE_B(slot, k0)                                        \
  { gl_lds16(bG0 + (k0),            &Bs[slot][wL0]);             \
    gl_lds16(bG0 + (k0) + 16*KDIM,  &Bs[slot][wL0 + 512]); }

  // read-side swizzled k-granule, key=(row>>1)&3 = (l>>1)&3
  const int eoff = (((l >> 4) ^ ((l >> 1) & 3)) * 8);
  const int aRowOff = (wr * 128 + (l & 15)) * 32 + eoff;   // + m*512
  const int bRowOff = (wc * 64 + (l & 15)) * 32 + eoff;    // + n*512

  auto compute = [&](int as_, int bs_) {
    const unsigned short* Ab = &As[as_][0];
    const unsigned short* Bb = &Bs[bs_][0];
    bf16x8 af[8], bfr[4];
#pragma unroll
    for (int m = 0; m < 8; ++m) af[m] = *(const bf16x8*)&Ab[aRowOff + m * 512];
#pragma unroll
    for (int n = 0; n < 4; ++n) bfr[n] = *(const bf16x8*)&Bb[bRowOff + n * 512];
    __builtin_amdgcn_s_setprio(1);
#pragma unroll
    for (int m = 0; m < 8; ++m)
#pragma unroll
      for (int n = 0; n < 4; ++n)
        acc[m][n] = __builtin_amdgcn_mfma_f32_16x16x32_bf16(af[m], bfr[n], acc[m][n], 0, 0, 0);
    __builtin_amdgcn_s_setprio(0);
  };

  // prologue: A0,B0,A1,B1,B2 issued; wait A0,B0 landed (leave A1,B1,B2 = 6 calls)
  STAGE_A(0, 0);
  STAGE_B(0, 0);
  STAGE_A(1, 32);
  STAGE_B(1, 32);
  STAGE_B(2, 64);
  asm volatile("s_waitcnt vmcnt(6)" ::: "memory");
  __builtin_amdgcn_s_barrier();
  __builtin_amdgcn_sched_barrier(0);

  for (int t = 0; t < NKT - 2; ++t) {
    STAGE_A((t + 1) & 1, (t + 1) * 32);      // WAR: slot held A(t-1), reads done
    STAGE_B((t + 2) % 3, (t + 2) * 32);      // WAR: slot held B(t-1), reads done
    compute(t & 1, t % 3);
    asm volatile("s_waitcnt vmcnt(2)" ::: "memory");  // A(t+1),B(t+1) landed
    __builtin_amdgcn_s_barrier();
    __builtin_amdgcn_sched_barrier(0);
  }
  // iter NKT-2: stage last A only
  STAGE_A((NKT - 1) & 1, (NKT - 1) * 32);
  compute((NKT - 2) & 1, (NKT - 2) % 3);
  asm volatile("s_waitcnt vmcnt(0)" ::: "memory");    // A(NKT-1),B(NKT-1) landed
  __builtin_amdgcn_s_barrier();
  __builtin_amdgcn_sched_barrier(0);
  compute((NKT - 1) & 1, (NKT - 1) % 3);
#undef STAGE_A
#undef STAGE_B

  const int rbase = bm * 256 + wr * 128;
  const int cbase = bn * 256 + wc * 64;
  const int lr4 = (l >> 4) * 4;
  const int lc16 = l & 15;

  if constexpr (EPI == 0) {
#pragma unroll
    for (int m = 0; m < 8; ++m)
#pragma unroll
      for (int n = 0; n < 4; ++n) {
        const int col = cbase + n * 16 + lc16;
#pragma unroll
        for (int j2 = 0; j2 < 4; ++j2) {
          const int row = rbase + m * 16 + lr4 + j2;
          ob[(long)row * NC + col] = f2bf(acc[m][n][j2]);
        }
      }
  } else {
#pragma unroll
    for (int m = 0; m < 8; ++m)
#pragma unroll
      for (int n = 0; n < 4; ++n) {
        const int col = cbase + n * 16 + lc16;
#pragma unroll
        for (int j2 = 0; j2 < 4; ++j2) {
          const int row = rbase + m * 16 + lr4 + j2;
          const long o = (long)row * NC + col;
          of[o] = resid[o] + acc[m][n][j2];
        }
      }
  }
}

// ------- scan pass 1 (4-way parallel, RECOMPUTE): Llast, bout + seg spills --------
__global__ __launch_bounds__(256) void scan1_k(const unsigned short* __restrict__ fu,
                                               const float* __restrict__ dt_bias,
                                               const float2* __restrict__ tab,
                                               float* __restrict__ Llast,
                                               float* __restrict__ bout,
                                               float* __restrict__ segb,
                                               float* __restrict__ scab) {
  __shared__ float Ssum[4][64];
  __shared__ float Ssca[4][64];
  const int t = threadIdx.x;
  const int lane = t & 63, seg = t >> 6;
  const int cid = blockIdx.x * 64 + lane;     // 0..131071
  const int d = cid & 1023;
  const int ch = (cid >> 10) & 31;
  const int b = cid >> 15;
  const long base = ((long)b * NSEQ + ch * CHUNKC + seg * 64) * 3072 + d;
  const float bias = dt_bias[d];
  const int f = d & 31;
  const bool hi = (d & 32) != 0;
  const int po = hi ? -32 : 32;
  float segsum = 0.f;
#pragma unroll 8
  for (int i = 0; i < 64; ++i)
    segsum += softplus_cl(bf2f(fu[base + (long)i * 3072]) + bias);
  Ssum[seg][lane] = segsum;
  segb[seg * NCOL + cid] = segsum;
  __syncthreads();
  float basev = 0.f;
  for (int k = 0; k < seg; ++k) basev -= Ssum[k][lane];   // wave-uniform trip count
  const int posbase = ch * CHUNKC + seg * 64;
  float run = basev, s = 0.f;
#pragma unroll 4
  for (int i = 0; i < 64; ++i) {
    const long o = base + (long)i * 3072;
    const float dtv = softplus_cl(bf2f(fu[o]) + bias);
    const float own = bf2f(fu[o + 1024]);
    const float oth = bf2f(fu[o + 1024 + po]);
    const float2 cs = tab[(posbase + i) * 32 + f];
    const float vr = own * cs.x + (hi ? oth * cs.y : -oth * cs.y);
    run -= dtv;
    const float L = fminf(fmaxf(run, -20.f), 0.f);
    s += exp2f(-LOG2E * L) * (vr * dtv);
  }
  Ssca[seg][lane] = s;
  scab[seg * NCOL + cid] = s;
  __syncthreads();
  if (seg == 0) {
    const float tot = Ssum[0][lane] + Ssum[1][lane] + Ssum[2][lane] + Ssum[3][lane];
    const float Ll = fminf(fmaxf(-tot, -20.f), 0.f);
    const float st = Ssca[0][lane] + Ssca[1][lane] + Ssca[2][lane] + Ssca[3][lane];
    Llast[cid] = Ll;
    bout[cid] = exp2f(LOG2E * Ll) * st;
  }
}

// ------- scan pass 3 (single pass, INLINE carry): final bf16 IN PLACE over v ------
__global__ __launch_bounds__(256) void scan3_k(unsigned short* fu,
                                               const float* __restrict__ dt_bias,
                                               const float2* __restrict__ tab,
                                               const float* __restrict__ Llast,
                                               const float* __restrict__ bout,
                                               const float* __restrict__ segb,
                                               const float* __restrict__ scab) {
  const int t = threadIdx.x;
  const int lane = t & 63, seg = t >> 6;
  const int cid = blockIdx.x * 64 + lane;
  const int d = cid & 1023;
  const int ch = (cid >> 10) & 31;
  const int b = cid >> 15;
  const long base = ((long)b * NSEQ + ch * CHUNKC + seg * 64) * 3072 + d;
  const float bias = dt_bias[d];
  const int f = d & 31;
  const bool hi = (d & 32) != 0;
  const int po = hi ? -32 : 32;
  // ---- inline scan2: carry for (b, ch, d), identical order to the old kernel ----
  const long cb2 = (long)b * (NCHK * DMODEL) + d;
  float run2 = 0.f, stab = -1e30f;
#pragma unroll
  for (int c2 = 0; c2 < NCHK; ++c2) {
    run2 += Llast[cb2 + c2 * DMODEL];
    stab = fmaxf(stab, fminf(fmaxf(run2, -80.f), 0.f));
  }
  float ce = 0.f;
  {
    float run3 = 0.f, acc = 0.f;
    for (int c2 = 0; c2 <= ch; ++c2) {        // block-uniform bound
      run3 += Llast[cb2 + c2 * DMODEL];
      const float cdv = fminf(fmaxf(run3, -80.f), 0.f);
      const float ncd = fminf(fmaxf(cdv - stab, -20.f), 0.f);
      if (c2 == ch) ce = acc * exp2f(LOG2E * ncd);
      else acc += bout[cb2 + c2 * DMODEL] * exp2f(-LOG2E * ncd);
    }
  }
  // ---- segment bases from scan1 spills ----
  float basev = 0.f, sbase = 0.f;
  for (int k = 0; k < seg; ++k) {             // wave-uniform trip count
    basev -= segb[k * NCOL + cid];
    sbase += scab[k * NCOL + cid];
  }
  const int posbase = ch * CHUNKC + seg * 64;
  float run = basev, s = sbase;
#pragma unroll 4
  for (int i = 0; i < 64; ++i) {
    const long o = base + (long)i * 3072;
    const float dtv = softplus_cl(bf2f(fu[o]) + bias);
    const float own = bf2f(fu[o + 1024]);
    const float oth = bf2f(fu[o + 1024 + po]);
    const float2 cs = tab[(posbase + i) * 32 + f];
    const float vr = own * cs.x + (hi ? oth * cs.y : -oth * cs.y);
    run -= dtv;
    const float L = fminf(fmaxf(run, -20.f), 0.f);
    s += exp2f(-LOG2E * L) * (vr * dtv);
    fu[o + 1024] = f2bf(exp2f(LOG2E * L) * (s + ce));
  }
}

// -------- head mix (16x16) * sigmoid(gate_raw) -> A2 bf16 (ushort2 packed) --------
__global__ __launch_bounds__(256) void headmix_k(const unsigned short* __restrict__ fu,
                                                 const float* __restrict__ hm,
                                                 unsigned short* __restrict__ A2) {
  __shared__ float mixs[256];
  const int t = threadIdx.x;
  mixs[t] = hm[t];
  __syncthreads();
  const long row = (long)blockIdx.x * 8 + (t >> 5);   // 8 rows/block
  const int dd = (t & 31) * 2;
  const unsigned short* fv0 = fu + row * 3072 + 1024 + dd;   // final (over v)
  const unsigned short* gv0 = fu + row * 3072 + 2048 + dd;   // gate raw
  unsigned fvp[16];
#pragma unroll
  for (int h = 0; h < 16; ++h) fvp[h] = *(const unsigned*)(fv0 + h * 64);
#pragma unroll
  for (int m = 0; m < 16; ++m) {
    float o0 = 0.f, o1 = 0.f;
#pragma unroll
    for (int h = 0; h < 16; ++h) {
      const float mh = mixs[h * 16 + m];
      o0 += bf2f((unsigned short)(fvp[h] & 0xffffu)) * mh;
      o1 += bf2f((unsigned short)(fvp[h] >> 16)) * mh;
    }
    const unsigned gp = *(const unsigned*)(gv0 + m * 64);
    const unsigned r0 = (unsigned)f2bf(o0 * sigm(bf2f((unsigned short)(gp & 0xffffu))));
    const unsigned r1 = (unsigned)f2bf(o1 * sigm(bf2f((unsigned short)(gp >> 16))));
    *(unsigned*)(A2 + row * DMODEL + m * 64 + dd) = r0 | (r1 << 16);
  }
}

extern "C" void kernel_launch(void* const* d_in, const int* in_sizes, int n_in,
                              void* d_out, int out_size, void* d_ws, size_t ws_size,
                              hipStream_t stream) {
  const float* x        = (const float*)d_in[0];
  const float* nscale   = (const float*)d_in[1];
  const float* conv_w   = (const float*)d_in[2];
  const float* conv_b   = (const float*)d_in[3];
  const float* in_proj  = (const float*)d_in[4];
  const float* dt_bias  = (const float*)d_in[5];
  const float* head_mix = (const float*)d_in[6];
  const float* out_proj = (const float*)d_in[7];
  float* out = (float*)d_out;

  char* p = (char*)d_ws;
  unsigned short* W1T = (unsigned short*)p; p += (size_t)3072 * 1024 * 2;
  unsigned short* W2T = (unsigned short*)p; p += (size_t)1024 * 1024 * 2;
  float2* tab  = (float2*)p; p += (size_t)NSEQ * 32 * sizeof(float2);
  float* Llast = (float*)p;  p += (size_t)NCOL * 4;
  float* bout  = (float*)p;  p += (size_t)NCOL * 4;
  float* segb  = (float*)p;  p += (size_t)4 * NCOL * 4;
  float* scab  = (float*)p;  p += (size_t)4 * NCOL * 4;
  unsigned short* fusedb = (unsigned short*)p; p += (size_t)TOK * 3072 * 2;
  unsigned short* xc     = (unsigned short*)p; p += (size_t)TOK * DMODEL * 2; // reused: A2

  pre_k<<<5120 + TOK / 8, 256, 0, stream>>>(x, nscale, conv_w, conv_b, xc,
                                            in_proj, out_proj, W1T, W2T, tab);

  gemm_bt<0, 12, 6><<<dim3(12, 128), 512, 0, stream>>>(xc, W1T, fusedb, nullptr, nullptr);
  scan1_k<<<2048, 256, 0, stream>>>(fusedb, dt_bias, tab, Llast, bout, segb, scab);
  scan3_k<<<2048, 256, 0, stream>>>(fusedb, dt_bias, tab, Llast, bout, segb, scab);
  headmix_k<<<TOK / 8, 256, 0, stream>>>(fusedb, head_mix, xc /* A2 */);
  gemm_bt<1, 4, 4><<<dim3(4, 128), 512, 0, stream>>>(xc, W2T, nullptr, out, x);
}

// Round 16
// 565.086 us; speedup vs baseline: 4.9019x; 1.0999x over previous
//
#include <hip/hip_runtime.h>

#define TOK 32768          // B*N
#define DMODEL 1024
#define NSEQ 8192
#define NCHK 32            // chunks per sequence
#define CHUNKC 256
#define KDIM 1024
#define NCOL 131072        // B*NCHK*DMODEL scan columns
#define LOG2E 1.44269504f

typedef __attribute__((ext_vector_type(8))) short bf16x8;
typedef __attribute__((ext_vector_type(4))) float f32x4;

__device__ __forceinline__ unsigned short f2bf(float f) {
  unsigned u = __float_as_uint(f);
  u += 0x7fffu + ((u >> 16) & 1u);
  return (unsigned short)(u >> 16);
}
__device__ __forceinline__ float bf2f(unsigned short h) {
  return __uint_as_float(((unsigned)h) << 16);
}
__device__ __forceinline__ float sigm(float x) {   // sigmoid via exp2+rcp
  return __builtin_amdgcn_rcpf(1.f + exp2f(-LOG2E * x));
}
__device__ __forceinline__ float softplus_cl(float a) {
  const float e2 = exp2f(-LOG2E * fabsf(a));
  const float sp = fmaxf(a, 0.f) + 0.69314718f * log2f(1.f + e2);
  return fminf(fmaxf(sp, 0.001f), 2.0f);
}

typedef __attribute__((address_space(3))) unsigned int lds_u32_t;
typedef const __attribute__((address_space(1))) unsigned int glb_u32_t;

__device__ __forceinline__ void gl_lds16(const void* g, void* l) {
  __builtin_amdgcn_global_load_lds((glb_u32_t*)g, (lds_u32_t*)l, 16, 0, 0);
}

// ------ merged pre-pass: {W1T,W2T transpose->bf16, RoPE table} + rmsconv ----------
__global__ __launch_bounds__(256) void pre_k(const float* __restrict__ x,
                                             const float* __restrict__ scale,
                                             const float* __restrict__ cw,
                                             const float* __restrict__ cbias,
                                             unsigned short* __restrict__ xc,
                                             const float* __restrict__ w1,
                                             const float* __restrict__ w2,
                                             unsigned short* __restrict__ w1t,
                                             unsigned short* __restrict__ w2t,
                                             float2* __restrict__ tab) {
  __shared__ float tile[32][33];
  __shared__ float red[11][4];
  const int bid = blockIdx.x;
  const int t = threadIdx.x;
  if (bid < 4096) {        // transpose W[R=1024][C] -> WT[C][1024]
    const float* in;
    unsigned short* out;
    int c0, r0;
    if (bid < 3072) { in = w1; out = w1t; c0 = (bid % 96) * 32; r0 = (bid / 96) * 32; }
    else            { in = w2; out = w2t; c0 = ((bid - 3072) & 31) * 32; r0 = ((bid - 3072) >> 5) * 32; }
    const int C = (bid < 3072) ? 3072 : 1024;
    const int tx = t & 31, ty = t >> 5;
#pragma unroll
    for (int i = 0; i < 32; i += 8)
      tile[ty + i][tx] = in[(long)(r0 + ty + i) * C + c0 + tx];
    __syncthreads();
#pragma unroll
    for (int i = 0; i < 32; i += 8)
      out[(long)(c0 + ty + i) * 1024 + r0 + tx] = f2bf(tile[tx][ty + i]);
  } else if (bid < 5120) { // RoPE table: 8192*32 entries
    const int i = (bid - 4096) * 256 + t;
    const int f = i & 31, n = i >> 5;
    const float invf = exp2f(-(float)f * (13.287712379549449f / 32.0f));
    const float ang = (float)n * invf;
    tab[i] = make_float2(cosf(ang), sinf(ang));
  } else {                 // fused RMSNorm + depthwise conv(K=4) + SiLU
    const long row0 = (long)(bid - 5120) * 8;
    const bool seqstart = ((row0 & (NSEQ - 1)) == 0);
    const float4 sc = ((const float4*)scale)[t];
    float4 vr[11];
#pragma unroll
    for (int i = 0; i < 11; ++i) {
      if (i < 3 && seqstart) {
        vr[i] = make_float4(0.f, 0.f, 0.f, 0.f);
      } else {
        vr[i] = ((const float4*)(x + (row0 - 3 + i) * DMODEL))[t];
      }
      float ss = vr[i].x * vr[i].x + vr[i].y * vr[i].y + vr[i].z * vr[i].z + vr[i].w * vr[i].w;
#pragma unroll
      for (int off = 32; off > 0; off >>= 1) ss += __shfl_down(ss, off);
      if ((t & 63) == 0) red[i][t >> 6] = ss;
    }
    __syncthreads();
#pragma unroll
    for (int i = 0; i < 11; ++i) {
      const float tot = red[i][0] + red[i][1] + red[i][2] + red[i][3];
      const float rr = rsqrtf(tot * (1.0f / DMODEL) + 1e-6f);
      vr[i].x = fminf(fmaxf(vr[i].x * rr * sc.x, -60000.f), 60000.f);
      vr[i].y = fminf(fmaxf(vr[i].y * rr * sc.y, -60000.f), 60000.f);
      vr[i].z = fminf(fmaxf(vr[i].z * rr * sc.z, -60000.f), 60000.f);
      vr[i].w = fminf(fmaxf(vr[i].w * rr * sc.w, -60000.f), 60000.f);
    }
    const int d0 = t * 4;
    float wl[4][4];
#pragma unroll
    for (int j = 0; j < 4; ++j) {
      const float4 t4 = *(const float4*)(cw + (d0 + j) * 4);
      wl[j][0] = t4.x; wl[j][1] = t4.y; wl[j][2] = t4.z; wl[j][3] = t4.w;
    }
    const float4 cb4 = ((const float4*)cbias)[t];
#pragma unroll
    for (int orow = 0; orow < 8; ++orow) {
      float o[4] = {0.f, 0.f, 0.f, 0.f};
#pragma unroll
      for (int k = 0; k < 4; ++k) {
        const float4 xv = vr[orow + k];
        o[0] += xv.x * wl[0][k]; o[1] += xv.y * wl[1][k];
        o[2] += xv.z * wl[2][k]; o[3] += xv.w * wl[3][k];
      }
      ushort4 st;
      { const float a = o[0] + cb4.x; st.x = f2bf(a * sigm(a)); }
      { const float a = o[1] + cb4.y; st.y = f2bf(a * sigm(a)); }
      { const float a = o[2] + cb4.z; st.z = f2bf(a * sigm(a)); }
      { const float a = o[3] + cb4.w; st.w = f2bf(a * sigm(a)); }
      *(ushort4*)(xc + (row0 + orow) * DMODEL + d0) = st;
    }
  }
}

// ---------------- GEMM (R6/R13-proven): 128x256 tile, 3-slot BK=32 ring -----------
// 4 waves each owning 128x64 (acc[8][4]); counted vmcnt(6) after compute; one raw
// barrier per ktile + sched_barrier pin; T5 setprio; T2 granule swizzle; supertiles.
// 72KB LDS -> 2 blocks/CU (the load-bearing property per R9/R15 post-mortems).
// EPI==0: plain bf16 store (3072 cols). EPI==1: resid+f32 (1024 cols).
template <int EPI, int NBN, int SBN>
__global__ __launch_bounds__(256) void gemm_bt(const unsigned short* __restrict__ A,
                                               const unsigned short* __restrict__ BT,
                                               unsigned short* __restrict__ ob,
                                               float* __restrict__ of,
                                               const float* __restrict__ resid) {
  __shared__ unsigned short As[3][128 * 32];
  __shared__ unsigned short Bs[3][256 * 32];
  const int tid = threadIdx.x;
  const int l = tid & 63;
  const int w = tid >> 6;            // wave id = n-quadrant (0..3)
  constexpr int NC = (EPI == 0) ? 3072 : 1024;
  constexpr int NKT = KDIM / 32;

  constexpr int BPS = 4 * SBN;
  constexpr int NBNS = NBN / SBN;
  const int lin = blockIdx.y * NBN + blockIdx.x;
  const int xcd = lin & 7;
  const int g = lin >> 3;
  const int s = g / BPS;
  const int r = g - s * BPS;
  const int bmo = r / SBN;
  const int bno = r - bmo * SBN;
  const int bmS = s / NBNS;
  const int bnS = s - bmS * NBNS;
  const int bm = xcd * 32 + bmS * 4 + bmo;
  const int bn = bnS * SBN + bno;

  f32x4 acc[8][4];
#pragma unroll
  for (int m = 0; m < 8; ++m)
#pragma unroll
    for (int n = 0; n < 4; ++n) acc[m][n] = {0.f, 0.f, 0.f, 0.f};

  const int srcc = (((l & 3) ^ ((l >> 3) & 3)) * 8);
  const unsigned short* aG0 = A + ((long)(bm * 128 + w * 32 + (l >> 2))) * KDIM + srcc;
  const unsigned short* bG0 = BT + ((long)(bn * 256 + w * 64 + (l >> 2))) * KDIM + srcc;
  const int aLo = (w * 32) * 32;
  const int bLo = (w * 64) * 32;

#define STAGE(buf, k0)                                           \
  {                                                              \
    gl_lds16(aG0 + (k0),             &As[buf][aLo]);             \
    gl_lds16(aG0 + (k0) + 16 * KDIM, &As[buf][aLo + 512]);       \
    gl_lds16(bG0 + (k0),             &Bs[buf][bLo]);             \
    gl_lds16(bG0 + (k0) + 16 * KDIM, &Bs[buf][bLo + 512]);       \
    gl_lds16(bG0 + (k0) + 32 * KDIM, &Bs[buf][bLo + 1024]);      \
    gl_lds16(bG0 + (k0) + 48 * KDIM, &Bs[buf][bLo + 1536]);      \
  }

  const int eoff = (((l >> 4) ^ ((l >> 1) & 3)) * 8);
  const int arow0 = (l & 15) * 32 + eoff;
  const int brow0 = (w * 64 + (l & 15)) * 32 + eoff;

  auto compute = [&](int cur) {
    const unsigned short* Ab = &As[cur][0];
    const unsigned short* Bb = &Bs[cur][0];
    bf16x8 af[8], bfr[4];
#pragma unroll
    for (int m = 0; m < 8; ++m) af[m] = *(const bf16x8*)&Ab[arow0 + m * 512];
#pragma unroll
    for (int n = 0; n < 4; ++n) bfr[n] = *(const bf16x8*)&Bb[brow0 + n * 512];
    __builtin_amdgcn_s_setprio(1);
#pragma unroll
    for (int m = 0; m < 8; ++m)
#pragma unroll
      for (int n = 0; n < 4; ++n)
        acc[m][n] = __builtin_amdgcn_mfma_f32_16x16x32_bf16(af[m], bfr[n], acc[m][n], 0, 0, 0);
    __builtin_amdgcn_s_setprio(0);
  };

  STAGE(0, 0);
  STAGE(1, 32);
  asm volatile("s_waitcnt vmcnt(6)" ::: "memory");
  int cur = 0, nxt = 2;
  for (int t = 0; t < NKT - 2; ++t) {
    __builtin_amdgcn_s_barrier();
    __builtin_amdgcn_sched_barrier(0);
    STAGE(nxt, (t + 2) * 32);
    compute(cur);
    asm volatile("s_waitcnt vmcnt(6)" ::: "memory");
    cur = (cur == 2) ? 0 : cur + 1;
    nxt = (nxt == 2) ? 0 : nxt + 1;
  }
  __builtin_amdgcn_s_barrier();
  __builtin_amdgcn_sched_barrier(0);
  compute(cur);
  asm volatile("s_waitcnt vmcnt(0)" ::: "memory");
  cur = (cur == 2) ? 0 : cur + 1;
  __builtin_amdgcn_s_barrier();
  __builtin_amdgcn_sched_barrier(0);
  compute(cur);
#undef STAGE

  const int rbase = bm * 128;
  const int cbase = bn * 256 + w * 64;
  const int lr4 = (l >> 4) * 4;
  const int lc16 = l & 15;

  if constexpr (EPI == 0) {
#pragma unroll
    for (int m = 0; m < 8; ++m)
#pragma unroll
      for (int n = 0; n < 4; ++n) {
        const int col = cbase + n * 16 + lc16;
#pragma unroll
        for (int j2 = 0; j2 < 4; ++j2) {
          const int row = rbase + m * 16 + lr4 + j2;
          ob[(long)row * NC + col] = f2bf(acc[m][n][j2]);
        }
      }
  } else {
#pragma unroll
    for (int m = 0; m < 8; ++m)
#pragma unroll
      for (int n = 0; n < 4; ++n) {
        const int col = cbase + n * 16 + lc16;
#pragma unroll
        for (int j2 = 0; j2 < 4; ++j2) {
          const int row = rbase + m * 16 + lr4 + j2;
          const long o = (long)row * NC + col;
          of[o] = resid[o] + acc[m][n][j2];
        }
      }
  }
}

// ------- scan pass 1 (4-way parallel, RECOMPUTE): Llast, bout + seg spills --------
__global__ __launch_bounds__(256) void scan1_k(const unsigned short* __restrict__ fu,
                                               const float* __restrict__ dt_bias,
                                               const float2* __restrict__ tab,
                                               float* __restrict__ Llast,
                                               float* __restrict__ bout,
                                               float* __restrict__ segb,
                                               float* __restrict__ scab) {
  __shared__ float Ssum[4][64];
  __shared__ float Ssca[4][64];
  const int t = threadIdx.x;
  const int lane = t & 63, seg = t >> 6;
  const int cid = blockIdx.x * 64 + lane;     // 0..131071
  const int d = cid & 1023;
  const int ch = (cid >> 10) & 31;
  const int b = cid >> 15;
  const long base = ((long)b * NSEQ + ch * CHUNKC + seg * 64) * 3072 + d;
  const float bias = dt_bias[d];
  const int f = d & 31;
  const bool hi = (d & 32) != 0;
  const int po = hi ? -32 : 32;
  float segsum = 0.f;
#pragma unroll 8
  for (int i = 0; i < 64; ++i)
    segsum += softplus_cl(bf2f(fu[base + (long)i * 3072]) + bias);
  Ssum[seg][lane] = segsum;
  segb[seg * NCOL + cid] = segsum;
  __syncthreads();
  float basev = 0.f;
  for (int k = 0; k < seg; ++k) basev -= Ssum[k][lane];   // wave-uniform trip count
  const int posbase = ch * CHUNKC + seg * 64;
  float run = basev, s = 0.f;
#pragma unroll 4
  for (int i = 0; i < 64; ++i) {
    const long o = base + (long)i * 3072;
    const float dtv = softplus_cl(bf2f(fu[o]) + bias);
    const float own = bf2f(fu[o + 1024]);
    const float oth = bf2f(fu[o + 1024 + po]);
    const float2 cs = tab[(posbase + i) * 32 + f];
    const float vr = own * cs.x + (hi ? oth * cs.y : -oth * cs.y);
    run -= dtv;
    const float L = fminf(fmaxf(run, -20.f), 0.f);
    s += exp2f(-LOG2E * L) * (vr * dtv);
  }
  Ssca[seg][lane] = s;
  scab[seg * NCOL + cid] = s;
  __syncthreads();
  if (seg == 0) {
    const float tot = Ssum[0][lane] + Ssum[1][lane] + Ssum[2][lane] + Ssum[3][lane];
    const float Ll = fminf(fmaxf(-tot, -20.f), 0.f);
    const float st = Ssca[0][lane] + Ssca[1][lane] + Ssca[2][lane] + Ssca[3][lane];
    Llast[cid] = Ll;
    bout[cid] = exp2f(LOG2E * Ll) * st;
  }
}

// ------- scan pass 3 (single pass, INLINE carry): final bf16 IN PLACE over v ------
__global__ __launch_bounds__(256) void scan3_k(unsigned short* fu,
                                               const float* __restrict__ dt_bias,
                                               const float2* __restrict__ tab,
                                               const float* __restrict__ Llast,
                                               const float* __restrict__ bout,
                                               const float* __restrict__ segb,
                                               const float* __restrict__ scab) {
  const int t = threadIdx.x;
  const int lane = t & 63, seg = t >> 6;
  const int cid = blockIdx.x * 64 + lane;
  const int d = cid & 1023;
  const int ch = (cid >> 10) & 31;
  const int b = cid >> 15;
  const long base = ((long)b * NSEQ + ch * CHUNKC + seg * 64) * 3072 + d;
  const float bias = dt_bias[d];
  const int f = d & 31;
  const bool hi = (d & 32) != 0;
  const int po = hi ? -32 : 32;
  // ---- inline scan2: carry for (b, ch, d), identical order to the old kernel ----
  const long cb2 = (long)b * (NCHK * DMODEL) + d;
  float run2 = 0.f, stab = -1e30f;
#pragma unroll
  for (int c2 = 0; c2 < NCHK; ++c2) {
    run2 += Llast[cb2 + c2 * DMODEL];
    stab = fmaxf(stab, fminf(fmaxf(run2, -80.f), 0.f));
  }
  float ce = 0.f;
  {
    float run3 = 0.f, acc = 0.f;
    for (int c2 = 0; c2 <= ch; ++c2) {        // block-uniform bound
      run3 += Llast[cb2 + c2 * DMODEL];
      const float cdv = fminf(fmaxf(run3, -80.f), 0.f);
      const float ncd = fminf(fmaxf(cdv - stab, -20.f), 0.f);
      if (c2 == ch) ce = acc * exp2f(LOG2E * ncd);
      else acc += bout[cb2 + c2 * DMODEL] * exp2f(-LOG2E * ncd);
    }
  }
  // ---- segment bases from scan1 spills ----
  float basev = 0.f, sbase = 0.f;
  for (int k = 0; k < seg; ++k) {             // wave-uniform trip count
    basev -= segb[k * NCOL + cid];
    sbase += scab[k * NCOL + cid];
  }
  const int posbase = ch * CHUNKC + seg * 64;
  float run = basev, s = sbase;
#pragma unroll 4
  for (int i = 0; i < 64; ++i) {
    const long o = base + (long)i * 3072;
    const float dtv = softplus_cl(bf2f(fu[o]) + bias);
    const float own = bf2f(fu[o + 1024]);
    const float oth = bf2f(fu[o + 1024 + po]);
    const float2 cs = tab[(posbase + i) * 32 + f];
    const float vr = own * cs.x + (hi ? oth * cs.y : -oth * cs.y);
    run -= dtv;
    const float L = fminf(fmaxf(run, -20.f), 0.f);
    s += exp2f(-LOG2E * L) * (vr * dtv);
    fu[o + 1024] = f2bf(exp2f(LOG2E * L) * (s + ce));
  }
}

// -------- head mix (16x16) * sigmoid(gate_raw) -> A2 bf16 (ushort2 packed) --------
__global__ __launch_bounds__(256) void headmix_k(const unsigned short* __restrict__ fu,
                                                 const float* __restrict__ hm,
                                                 unsigned short* __restrict__ A2) {
  __shared__ float mixs[256];
  const int t = threadIdx.x;
  mixs[t] = hm[t];
  __syncthreads();
  const long row = (long)blockIdx.x * 8 + (t >> 5);   // 8 rows/block
  const int dd = (t & 31) * 2;
  const unsigned short* fv0 = fu + row * 3072 + 1024 + dd;   // final (over v)
  const unsigned short* gv0 = fu + row * 3072 + 2048 + dd;   // gate raw
  unsigned fvp[16];
#pragma unroll
  for (int h = 0; h < 16; ++h) fvp[h] = *(const unsigned*)(fv0 + h * 64);
#pragma unroll
  for (int m = 0; m < 16; ++m) {
    float o0 = 0.f, o1 = 0.f;
#pragma unroll
    for (int h = 0; h < 16; ++h) {
      const float mh = mixs[h * 16 + m];
      o0 += bf2f((unsigned short)(fvp[h] & 0xffffu)) * mh;
      o1 += bf2f((unsigned short)(fvp[h] >> 16)) * mh;
    }
    const unsigned gp = *(const unsigned*)(gv0 + m * 64);
    const unsigned r0 = (unsigned)f2bf(o0 * sigm(bf2f((unsigned short)(gp & 0xffffu))));
    const unsigned r1 = (unsigned)f2bf(o1 * sigm(bf2f((unsigned short)(gp >> 16))));
    *(unsigned*)(A2 + row * DMODEL + m * 64 + dd) = r0 | (r1 << 16);
  }
}

extern "C" void kernel_launch(void* const* d_in, const int* in_sizes, int n_in,
                              void* d_out, int out_size, void* d_ws, size_t ws_size,
                              hipStream_t stream) {
  const float* x        = (const float*)d_in[0];
  const float* nscale   = (const float*)d_in[1];
  const float* conv_w   = (const float*)d_in[2];
  const float* conv_b   = (const float*)d_in[3];
  const float* in_proj  = (const float*)d_in[4];
  const float* dt_bias  = (const float*)d_in[5];
  const float* head_mix = (const float*)d_in[6];
  const float* out_proj = (const float*)d_in[7];
  float* out = (float*)d_out;

  char* p = (char*)d_ws;
  unsigned short* W1T = (unsigned short*)p; p += (size_t)3072 * 1024 * 2;
  unsigned short* W2T = (unsigned short*)p; p += (size_t)1024 * 1024 * 2;
  float2* tab  = (float2*)p; p += (size_t)NSEQ * 32 * sizeof(float2);
  float* Llast = (float*)p;  p += (size_t)NCOL * 4;
  float* bout  = (float*)p;  p += (size_t)NCOL * 4;
  float* segb  = (float*)p;  p += (size_t)4 * NCOL * 4;
  float* scab  = (float*)p;  p += (size_t)4 * NCOL * 4;
  unsigned short* fusedb = (unsigned short*)p; p += (size_t)TOK * 3072 * 2;
  unsigned short* xc     = (unsigned short*)p; p += (size_t)TOK * DMODEL * 2; // reused: A2

  pre_k<<<5120 + TOK / 8, 256, 0, stream>>>(x, nscale, conv_w, conv_b, xc,
                                            in_proj, out_proj, W1T, W2T, tab);

  gemm_bt<0, 12, 6><<<dim3(12, 256), 256, 0, stream>>>(xc, W1T, fusedb, nullptr, nullptr);
  scan1_k<<<2048, 256, 0, stream>>>(fusedb, dt_bias, tab, Llast, bout, segb, scab);
  scan3_k<<<2048, 256, 0, stream>>>(fusedb, dt_bias, tab, Llast, bout, segb, scab);
  headmix_k<<<TOK / 8, 256, 0, stream>>>(fusedb, head_mix, xc /* A2 */);
  gemm_bt<1, 4, 4><<<dim3(4, 256), 256, 0, stream>>>(xc, W2T, nullptr, out, x);
}